// Round 8
// baseline (288.055 us; speedup 1.0000x reference)
//
#include <hip/hip_runtime.h>

#define NN 8192
#define CIN 32
#define COUT 64
#define KF 5

typedef __attribute__((ext_vector_type(8))) short bf16x8_t;
typedef __attribute__((ext_vector_type(4))) float f32x4_t;

// fp32 -> bf16 RNE
__device__ __forceinline__ short f2bf(float f) {
    unsigned u = __builtin_bit_cast(unsigned, f);
    unsigned r = (u + 0x7FFFu + ((u >> 16) & 1u)) >> 16;
    return (short)(unsigned short)r;
}

__device__ __forceinline__ bf16x8_t cvt8(float4 a, float4 b) {
    bf16x8_t v;
    v[0] = f2bf(a.x); v[1] = f2bf(a.y); v[2] = f2bf(a.z); v[3] = f2bf(a.w);
    v[4] = f2bf(b.x); v[5] = f2bf(b.y); v[6] = f2bf(b.z); v[7] = f2bf(b.w);
    return v;
}

// Async global->LDS DMA: 16 B/lane; LDS dest = wave-uniform base + lane*16.
typedef const __attribute__((address_space(1))) void* as1_t;
typedef __attribute__((address_space(3))) void* as3_t;
__device__ __forceinline__ void gll16(const void* g, void* l) {
    __builtin_amdgcn_global_load_lds((as1_t)g, (as3_t)l, 16, 0, 0);
}

// x fp32 -> bf16 (CIN*NN/4 = 65536 quads; grid 256x256)
__global__ void cvt_kernel(const float* __restrict__ src, short* __restrict__ dst) {
    int idx = blockIdx.x * 256 + threadIdx.x;
    float4 v = reinterpret_cast<const float4*>(src)[idx];
    short4 o;
    o.x = f2bf(v.x); o.y = f2bf(v.y); o.z = f2bf(v.z); o.w = f2bf(v.w);
    reinterpret_cast<short4*>(dst)[idx] = o;
}

// D layout (m89, validated R1-R7): col=lane&15 -> i, row=(lane>>4)*4+reg -> c
__device__ __forceinline__ void stash_partials(float* red, int wave, int g, int r,
                                               const f32x4_t& acc0, const f32x4_t& acc1) {
    const int base = wave * 512 + g * 64 + r;
#pragma unroll
    for (int t = 0; t < 4; ++t) {
        red[base + t * 16]       = acc0[t];
        red[base + t * 16 + 256] = acc1[t];
    }
}

__device__ __forceinline__ float reduce8(const float* red, int tid) {
    float s = red[tid];
#pragma unroll
    for (int w = 1; w < 8; ++w) s += red[w * 512 + tid];
    return s;
}

// ---- Pass 1: fp32 L staged via async DMA (wave-private D=2 ring), inline cvt,
// stash bf16 Lb; A = Tb0 (bf16 x) also DMA-staged. Grid 512, 8 waves, i-tile 16,
// wave K-range 1024 = 32 steps of 32.
// LDS/wave 8KB: L slots [0,2048)+[2048,4096) (fp32 2KB), A slots [4096,6144)+[6144,8192).
__global__ __launch_bounds__(512, 4) void pass1_kernel(
    const float* __restrict__ L, const short* __restrict__ Tb0,
    short* __restrict__ Lb, float* __restrict__ Tf1, short* __restrict__ Tb1)
{
    __shared__ float red[8 * 512];                 // 16 KB
    __shared__ __align__(16) char stage[8][8192];  // 64 KB
    const int tid = threadIdx.x, wave = tid >> 6, lane = tid & 63;
    const int g = lane >> 4, r = lane & 15;
    const int i0 = blockIdx.x * 16;
    const int jb = wave * 1024;
    char* st = stage[wave];

    // per-lane DMA sources (16B each)
    const float* sL  = L   + (size_t)(i0 + r) * NN + jb + g * 4;   // 4 fp32
    const short* sA0 = Tb0 + (size_t)r * NN        + jb + g * 8;   // 8 bf16, rows 0-15
    const short* sA1 = Tb0 + (size_t)(r + 16) * NN + jb + g * 8;   // rows 16-31
    short* dL = Lb + (size_t)(i0 + r) * NN + jb + g * 8;           // Lb store, 16B/lane

    // lane's LDS read offsets
    const int loL = (g >> 1) * 1024 + (g & 1) * 512 + r * 16;      // within 2KB L slot
    const int lo  = lane * 16;

    // prologue: steps 0,1 (4 DMA each: 2xL + 2xA)
    gll16(sL,       st + 0);
    gll16(sL + 16,  st + 1024);
    gll16(sA0,      st + 4096);
    gll16(sA1,      st + 5120);
    gll16(sL + 32,  st + 2048);
    gll16(sL + 48,  st + 3072);
    gll16(sA0 + 32, st + 6144);
    gll16(sA1 + 32, st + 7168);

    f32x4_t acc0 = {0.f,0.f,0.f,0.f};
    f32x4_t acc1 = {0.f,0.f,0.f,0.f};
#pragma unroll 2
    for (int t = 0; t < 32; ++t) {
        // wait for step t's 4 DMAs; allow store(t-1) + step(t+1)'s 4 to remain
        if (t == 0)      asm volatile("s_waitcnt vmcnt(4)" ::: "memory");
        else if (t < 31) asm volatile("s_waitcnt vmcnt(5)" ::: "memory");
        else             asm volatile("s_waitcnt vmcnt(1)" ::: "memory");
        const int sl = t & 1;
        float4 l0 = *(const float4*)(st + sl * 2048 + loL);
        float4 l1 = *(const float4*)(st + sl * 2048 + loL + 256);
        bf16x8_t a0 = *(const bf16x8_t*)(st + 4096 + sl * 2048 + lo);
        bf16x8_t a1 = *(const bf16x8_t*)(st + 4096 + sl * 2048 + 1024 + lo);
        bf16x8_t b = cvt8(l0, l1);
        *(bf16x8_t*)(dL + t * 32) = b;                         // counted store
        acc0 = __builtin_amdgcn_mfma_f32_16x16x32_bf16(a0, b, acc0, 0, 0, 0);
        acc1 = __builtin_amdgcn_mfma_f32_16x16x32_bf16(a1, b, acc1, 0, 0, 0);
        if (t < 30) {
            const int adv = (t + 2) * 32;
            asm volatile("s_waitcnt lgkmcnt(0)" ::: "memory"); // ds_reads done before slot reuse
            gll16(sL + adv,      st + sl * 2048);
            gll16(sL + adv + 16, st + sl * 2048 + 1024);
            gll16(sA0 + adv,     st + 4096 + sl * 2048);
            gll16(sA1 + adv,     st + 4096 + sl * 2048 + 1024);
        }
    }

    stash_partials(red, wave, g, r, acc0, acc1);
    __syncthreads();
    const int c = tid >> 4, il = tid & 15;
    const float val = reduce8(red, tid);
    const size_t off = (size_t)c * NN + i0 + il;
    Tf1[off] = val;
    Tb1[off] = f2bf(val);
}

// ---- Mid passes (2,3): all-bf16, DMA-staged. LDS/wave 6KB:
// L slots [0,1024)+[1024,2048); A slots [2048,4096)+[4096,6144).
__global__ __launch_bounds__(512, 4) void passmid_kernel(
    const short* __restrict__ Lbm, const short* __restrict__ A,
    const float* __restrict__ Tprev, float* __restrict__ Tf, short* __restrict__ Tb)
{
    __shared__ float red[8 * 512];                 // 16 KB
    __shared__ __align__(16) char stage[8][6144];  // 48 KB
    const int tid = threadIdx.x, wave = tid >> 6, lane = tid & 63;
    const int g = lane >> 4, r = lane & 15;
    const int i0 = blockIdx.x * 16;
    const int jb = wave * 1024;
    char* st = stage[wave];

    const short* sL  = Lbm + (size_t)(i0 + r) * NN + jb + g * 8;
    const short* sA0 = A   + (size_t)r * NN        + jb + g * 8;
    const short* sA1 = A   + (size_t)(r + 16) * NN + jb + g * 8;
    const int lo = lane * 16;

    gll16(sL,       st + 0);
    gll16(sA0,      st + 2048);
    gll16(sA1,      st + 3072);
    gll16(sL + 32,  st + 1024);
    gll16(sA0 + 32, st + 4096);
    gll16(sA1 + 32, st + 5120);

    f32x4_t acc0 = {0.f,0.f,0.f,0.f};
    f32x4_t acc1 = {0.f,0.f,0.f,0.f};
#pragma unroll 2
    for (int t = 0; t < 32; ++t) {
        if (t < 31) asm volatile("s_waitcnt vmcnt(3)" ::: "memory");
        else        asm volatile("s_waitcnt vmcnt(0)" ::: "memory");
        const int sl = t & 1;
        bf16x8_t b  = *(const bf16x8_t*)(st + sl * 1024 + lo);
        bf16x8_t a0 = *(const bf16x8_t*)(st + 2048 + sl * 2048 + lo);
        bf16x8_t a1 = *(const bf16x8_t*)(st + 2048 + sl * 2048 + 1024 + lo);
        acc0 = __builtin_amdgcn_mfma_f32_16x16x32_bf16(a0, b, acc0, 0, 0, 0);
        acc1 = __builtin_amdgcn_mfma_f32_16x16x32_bf16(a1, b, acc1, 0, 0, 0);
        if (t < 30) {
            const int adv = (t + 2) * 32;
            asm volatile("s_waitcnt lgkmcnt(0)" ::: "memory");
            gll16(sL + adv,  st + sl * 1024);
            gll16(sA0 + adv, st + 2048 + sl * 2048);
            gll16(sA1 + adv, st + 2048 + sl * 2048 + 1024);
        }
    }

    stash_partials(red, wave, g, r, acc0, acc1);
    __syncthreads();
    const int c = tid >> 4, il = tid & 15;
    const size_t off = (size_t)c * NN + i0 + il;
    const float val = 2.0f * reduce8(red, tid) - Tprev[off];
    Tf[off] = val;
    Tb[off] = f2bf(val);
}

// ---- Pass 4 + fused final einsum (T4 stays in LDS); theta read from global (L2-hot).
__global__ __launch_bounds__(512, 4) void pass4_kernel(
    const short* __restrict__ Lbm, const short* __restrict__ A,
    const float* __restrict__ Tf2, const float* __restrict__ x,
    const float* __restrict__ Tf1, const float* __restrict__ Tf3,
    const float* __restrict__ theta, const float* __restrict__ bias,
    float* __restrict__ y)
{
    __shared__ float red[8 * 512];
    __shared__ __align__(16) char stage[8][6144];
    const int tid = threadIdx.x, wave = tid >> 6, lane = tid & 63;
    const int g = lane >> 4, r = lane & 15;
    const int i0 = blockIdx.x * 16;
    const int jb = wave * 1024;
    char* st = stage[wave];

    const short* sL  = Lbm + (size_t)(i0 + r) * NN + jb + g * 8;
    const short* sA0 = A   + (size_t)r * NN        + jb + g * 8;
    const short* sA1 = A   + (size_t)(r + 16) * NN + jb + g * 8;
    const int lo = lane * 16;

    gll16(sL,       st + 0);
    gll16(sA0,      st + 2048);
    gll16(sA1,      st + 3072);
    gll16(sL + 32,  st + 1024);
    gll16(sA0 + 32, st + 4096);
    gll16(sA1 + 32, st + 5120);

    f32x4_t acc0 = {0.f,0.f,0.f,0.f};
    f32x4_t acc1 = {0.f,0.f,0.f,0.f};
#pragma unroll 2
    for (int t = 0; t < 32; ++t) {
        if (t < 31) asm volatile("s_waitcnt vmcnt(3)" ::: "memory");
        else        asm volatile("s_waitcnt vmcnt(0)" ::: "memory");
        const int sl = t & 1;
        bf16x8_t b  = *(const bf16x8_t*)(st + sl * 1024 + lo);
        bf16x8_t a0 = *(const bf16x8_t*)(st + 2048 + sl * 2048 + lo);
        bf16x8_t a1 = *(const bf16x8_t*)(st + 2048 + sl * 2048 + 1024 + lo);
        acc0 = __builtin_amdgcn_mfma_f32_16x16x32_bf16(a0, b, acc0, 0, 0, 0);
        acc1 = __builtin_amdgcn_mfma_f32_16x16x32_bf16(a1, b, acc1, 0, 0, 0);
        if (t < 30) {
            const int adv = (t + 2) * 32;
            asm volatile("s_waitcnt lgkmcnt(0)" ::: "memory");
            gll16(sL + adv,  st + sl * 1024);
            gll16(sA0 + adv, st + 2048 + sl * 2048);
            gll16(sA1 + adv, st + 2048 + sl * 2048 + 1024);
        }
    }

    stash_partials(red, wave, g, r, acc0, acc1);
    __syncthreads();
    {   // T4 column -> red[tid] (own-slot overwrite, safe)
        const int c = tid >> 4, il = tid & 15;
        red[tid] = 2.0f * reduce8(red, tid) - Tf2[(size_t)c * NN + i0 + il];
    }
    __syncthreads();

    const int o = tid >> 4, il = tid & 15;
    float a0 = bias[o], a1 = bias[o + 32];
    for (int cc = 0; cc < CIN; ++cc) {
        const size_t off = (size_t)cc * NN + i0 + il;
        const float t0 = x[off], t1 = Tf1[off], t2 = Tf2[off], t3 = Tf3[off];
        const float t4 = red[cc * 16 + il];
        const float* th0 = theta + ((size_t)o * CIN + cc) * KF;
        const float* th1 = theta + ((size_t)(o + 32) * CIN + cc) * KF;
        a0 += t0 * th0[0] + t1 * th0[1] + t2 * th0[2] + t3 * th0[3] + t4 * th0[4];
        a1 += t0 * th1[0] + t1 * th1[1] + t2 * th1[2] + t3 * th1[3] + t4 * th1[4];
    }
    y[(size_t)o * NN + i0 + il]        = a0;
    y[(size_t)(o + 32) * NN + i0 + il] = a1;
}

extern "C" void kernel_launch(void* const* d_in, const int* in_sizes, int n_in,
                              void* d_out, int out_size, void* d_ws, size_t ws_size,
                              hipStream_t stream) {
    const float* L     = (const float*)d_in[0];
    const float* x     = (const float*)d_in[1];
    const float* theta = (const float*)d_in[2];
    const float* bias  = (const float*)d_in[3];
    float* y = (float*)d_out;

    const size_t TE = (size_t)CIN * NN;
    const size_t LE = (size_t)NN * NN;

    // ws: Lb(128MB) | Tf1..Tf3 (1MB ea) | Tb0..Tb3 (0.5MB ea)
    short* Lb  = (short*)d_ws;
    float* Tf1 = (float*)(Lb + LE);
    float* Tf2 = Tf1 + TE;
    float* Tf3 = Tf2 + TE;
    short* Tb0 = (short*)(Tf3 + TE);
    short* Tb1 = Tb0 + TE;
    short* Tb2 = Tb1 + TE;
    short* Tb3 = Tb2 + TE;

    cvt_kernel<<<256, 256, 0, stream>>>(x, Tb0);
    pass1_kernel<<<NN / 16, 512, 0, stream>>>(L, Tb0, Lb, Tf1, Tb1);
    passmid_kernel<<<NN / 16, 512, 0, stream>>>(Lb, Tb1, x,   Tf2, Tb2);  // T2
    passmid_kernel<<<NN / 16, 512, 0, stream>>>(Lb, Tb2, Tf1, Tf3, Tb3);  // T3
    pass4_kernel<<<NN / 16, 512, 0, stream>>>(Lb, Tb3, Tf2, x, Tf1, Tf3,
                                              theta, bias, y);            // T4 + einsum
}

// Round 9
// 252.148 us; speedup vs baseline: 1.1424x; 1.1424x over previous
//
#include <hip/hip_runtime.h>

#define NN 8192
#define CIN 32
#define COUT 64
#define KF 5

typedef __attribute__((ext_vector_type(8))) short bf16x8_t;
typedef __attribute__((ext_vector_type(4))) float f32x4_t;

typedef const __attribute__((address_space(1))) void* as1_t;
typedef __attribute__((address_space(3))) void* as3_t;
__device__ __forceinline__ void gll16(const void* g, void* l) {
    __builtin_amdgcn_global_load_lds((as1_t)g, (as3_t)l, 16, 0, 0);
}

// fp32 -> bf16 RNE
__device__ __forceinline__ short f2bf(float f) {
    unsigned u = __builtin_bit_cast(unsigned, f);
    unsigned r = (u + 0x7FFFu + ((u >> 16) & 1u)) >> 16;
    return (short)(unsigned short)r;
}

__device__ __forceinline__ bf16x8_t cvt8(float4 a, float4 b) {
    bf16x8_t v;
    v[0] = f2bf(a.x); v[1] = f2bf(a.y); v[2] = f2bf(a.z); v[3] = f2bf(a.w);
    v[4] = f2bf(b.x); v[5] = f2bf(b.y); v[6] = f2bf(b.z); v[7] = f2bf(b.w);
    return v;
}

// x fp32 -> bf16
__global__ void cvt_kernel(const float* __restrict__ src, short* __restrict__ dst) {
    int idx = blockIdx.x * 256 + threadIdx.x;
    float4 v = reinterpret_cast<const float4*>(src)[idx];
    short4 o;
    o.x = f2bf(v.x); o.y = f2bf(v.y); o.z = f2bf(v.z); o.w = f2bf(v.w);
    reinterpret_cast<short4*>(dst)[idx] = o;
}

// D layout (m89): col=lane&15 -> i, row=(lane>>4)*4+reg -> c
__device__ __forceinline__ void stash_partials(float* red, int wave, int g, int r,
                                               const f32x4_t& acc0, const f32x4_t& acc1) {
    const int base = wave * 512 + g * 64 + r;
#pragma unroll
    for (int t = 0; t < 4; ++t) {
        red[base + t * 16]       = acc0[t];
        red[base + t * 16 + 256] = acc1[t];
    }
}

__device__ __forceinline__ float reduce8(const float* red, int tid) {
    float s = red[tid];
#pragma unroll
    for (int w = 1; w < 8; ++w) s += red[w * 512 + tid];
    return s;
}

// Mid-pass core: wave-private K-range 1024 = 16 chunks of 64 cols, depth-2 DMA ring.
// Lb tiled layout: per tile t (16 rows): 256KB; per wave-range: 32KB at w*32768;
// chunk c: 2KB linear at c*2048 = [m'(8-col grp)0..7][row0..15][16B].
// A image per chunk: 4KB = [m'0..7][row0..31][16B].
__device__ __forceinline__ void mid_core(const char* __restrict__ LbW,
                                         const short* __restrict__ Abase,
                                         int wave, int lane, char* stg,
                                         f32x4_t& acc0, f32x4_t& acc1)
{
    const int g = lane >> 4, r = lane & 15;
    const int kw = wave * 1024;
    const char* srcL = LbW + lane * 16;
    const short* sA0 = Abase + (size_t)(lane & 31) * NN + kw + (lane >> 5) * 8;

#pragma unroll
    for (int c0 = 0; c0 < 2; ++c0) {     // prologue: chunks 0,1 (6 DMA each)
        char* Ld = stg + c0 * 6144;
        char* Ad = Ld + 2048;
        gll16(srcL + c0 * 2048,        Ld);
        gll16(srcL + c0 * 2048 + 1024, Ld + 1024);
#pragma unroll
        for (int j = 0; j < 4; ++j) gll16(sA0 + c0 * 64 + j * 16, Ad + j * 1024);
    }

    for (int c = 0; c < 16; ++c) {
        if (c < 15) asm volatile("s_waitcnt vmcnt(6)" ::: "memory");
        else        asm volatile("s_waitcnt vmcnt(0)" ::: "memory");
        const char* Ld = stg + (c & 1) * 6144;
        const char* Ad = Ld + 2048;
#pragma unroll
        for (int kk = 0; kk < 2; ++kk) {
            bf16x8_t b  = *(const bf16x8_t*)(Ld + (kk * 4 + g) * 256 + r * 16);
            bf16x8_t a0 = *(const bf16x8_t*)(Ad + (kk * 4 + g) * 512 + r * 16);
            bf16x8_t a1 = *(const bf16x8_t*)(Ad + (kk * 4 + g) * 512 + 256 + r * 16);
            acc0 = __builtin_amdgcn_mfma_f32_16x16x32_bf16(a0, b, acc0, 0, 0, 0);
            acc1 = __builtin_amdgcn_mfma_f32_16x16x32_bf16(a1, b, acc1, 0, 0, 0);
        }
        if (c < 14) {
            asm volatile("s_waitcnt lgkmcnt(0)" ::: "memory");
            const int cn = c + 2;
            char* Ldn = stg + (cn & 1) * 6144;
            char* Adn = Ldn + 2048;
            gll16(srcL + cn * 2048,        Ldn);
            gll16(srcL + cn * 2048 + 1024, Ldn + 1024);
#pragma unroll
            for (int j = 0; j < 4; ++j) gll16(sA0 + cn * 64 + j * 16, Adn + j * 1024);
        }
    }
}

// ---- Pass 1: fp32 L staged via XOR-swizzled LDS image (256B runs/row), inline cvt,
// emit Lb in tiled layout with fully-linear 1KB stores. 16 chunks of 64 cols/wave.
__global__ __launch_bounds__(512, 2) void pass1_kernel(
    const float* __restrict__ L, const short* __restrict__ Tb0,
    char* __restrict__ LbC, float* __restrict__ Tf1, short* __restrict__ Tb1)
{
    __shared__ float red[4096];
    __shared__ __align__(16) char stg[8][16384];   // per wave: 2 slots x (L 4KB + A 4KB)
    const int tid = threadIdx.x, wave = tid >> 6, lane = tid & 63;
    const int g = lane >> 4, r = lane & 15;
    const int t = blockIdx.x, i0 = t * 16;
    const int kw = wave * 1024;
    char* st = stg[wave];

    // L DMA sources: instr j covers rows 4j+(lane>>4), 256B/row, pre-XOR'd source
    const int ls = lane >> 4, cb = (lane & 15) * 16;
    const float* baseL[4];
#pragma unroll
    for (int j = 0; j < 4; ++j) {
        const int row = 4 * j + ls;
        baseL[j] = L + (size_t)(i0 + row) * NN + kw + ((cb ^ ((row & 7) << 4)) >> 2);
    }
    const short* sA0 = Tb0 + (size_t)(lane & 31) * NN + kw + (lane >> 5) * 8;
    char* LbW = LbC + (size_t)t * 262144 + wave * 32768;

#pragma unroll
    for (int c0 = 0; c0 < 2; ++c0) {     // prologue: chunks 0,1 (8 DMA each)
        char* Ld = st + c0 * 8192;
        char* Ad = Ld + 4096;
#pragma unroll
        for (int j = 0; j < 4; ++j) gll16(baseL[j] + c0 * 64, Ld + j * 1024);
#pragma unroll
        for (int j = 0; j < 4; ++j) gll16(sA0 + c0 * 64 + j * 16, Ad + j * 1024);
    }

    f32x4_t acc0 = {0.f,0.f,0.f,0.f}, acc1 = {0.f,0.f,0.f,0.f};
    const int Xr = (r & 7) << 4;
    for (int c = 0; c < 16; ++c) {
        if (c == 0)      asm volatile("s_waitcnt vmcnt(8)" ::: "memory");
        else if (c < 15) asm volatile("s_waitcnt vmcnt(10)" ::: "memory");
        else             asm volatile("s_waitcnt vmcnt(2)" ::: "memory");
        const char* Ld = st + (c & 1) * 8192;
        const char* Ad = Ld + 4096;
#pragma unroll
        for (int kk = 0; kk < 2; ++kk) {
            float4 l0 = *(const float4*)(Ld + r * 256 + ((kk * 128 + g * 32) ^ Xr));
            float4 l1 = *(const float4*)(Ld + r * 256 + ((kk * 128 + g * 32 + 16) ^ Xr));
            bf16x8_t b = cvt8(l0, l1);
            *(bf16x8_t*)(LbW + c * 2048 + kk * 1024 + lane * 16) = b;  // linear 1KB store
            bf16x8_t a0 = *(const bf16x8_t*)(Ad + (kk * 4 + g) * 512 + r * 16);
            bf16x8_t a1 = *(const bf16x8_t*)(Ad + (kk * 4 + g) * 512 + 256 + r * 16);
            acc0 = __builtin_amdgcn_mfma_f32_16x16x32_bf16(a0, b, acc0, 0, 0, 0);
            acc1 = __builtin_amdgcn_mfma_f32_16x16x32_bf16(a1, b, acc1, 0, 0, 0);
        }
        if (c < 14) {
            asm volatile("s_waitcnt lgkmcnt(0)" ::: "memory");
            const int cn = c + 2;
            char* Ldn = st + (cn & 1) * 8192;
            char* Adn = Ldn + 4096;
#pragma unroll
            for (int j = 0; j < 4; ++j) gll16(baseL[j] + cn * 64, Ldn + j * 1024);
#pragma unroll
            for (int j = 0; j < 4; ++j) gll16(sA0 + cn * 64 + j * 16, Adn + j * 1024);
        }
    }

    stash_partials(red, wave, g, r, acc0, acc1);
    __syncthreads();
    const int c = tid >> 4, il = tid & 15;
    const float val = reduce8(red, tid);
    const size_t off = (size_t)c * NN + i0 + il;
    Tf1[off] = val;
    Tb1[off] = f2bf(val);
}

// ---- Mid passes (2,3): T_next = 2*(Tcur @ L^T) - Tprev
__global__ __launch_bounds__(512, 2) void passmid_kernel(
    const char* __restrict__ LbC, const short* __restrict__ A,
    const float* __restrict__ Tprev, float* __restrict__ Tf, short* __restrict__ Tb)
{
    __shared__ float red[4096];
    __shared__ __align__(16) char stg[8][12288];   // per wave: 2 slots x (L 2KB + A 4KB)
    const int tid = threadIdx.x, wave = tid >> 6, lane = tid & 63;
    const int g = lane >> 4, r = lane & 15;
    const int t = blockIdx.x, i0 = t * 16;

    f32x4_t acc0 = {0.f,0.f,0.f,0.f}, acc1 = {0.f,0.f,0.f,0.f};
    mid_core(LbC + (size_t)t * 262144 + wave * 32768, A, wave, lane, stg[wave], acc0, acc1);

    stash_partials(red, wave, g, r, acc0, acc1);
    __syncthreads();
    const int c = tid >> 4, il = tid & 15;
    const size_t off = (size_t)c * NN + i0 + il;
    const float val = 2.0f * reduce8(red, tid) - Tprev[off];
    Tf[off] = val;
    Tb[off] = f2bf(val);
}

// ---- Pass 4 + fused final einsum (T4 stays in LDS)
__global__ __launch_bounds__(512, 2) void pass4_kernel(
    const char* __restrict__ LbC, const short* __restrict__ A,
    const float* __restrict__ Tf2, const float* __restrict__ x,
    const float* __restrict__ Tf1, const float* __restrict__ Tf3,
    const float* __restrict__ theta, const float* __restrict__ bias,
    float* __restrict__ y)
{
    __shared__ float red[4096];
    __shared__ __align__(16) char stg[8][12288];
    const int tid = threadIdx.x, wave = tid >> 6, lane = tid & 63;
    const int g = lane >> 4, r = lane & 15;
    const int t = blockIdx.x, i0 = t * 16;

    f32x4_t acc0 = {0.f,0.f,0.f,0.f}, acc1 = {0.f,0.f,0.f,0.f};
    mid_core(LbC + (size_t)t * 262144 + wave * 32768, A, wave, lane, stg[wave], acc0, acc1);

    stash_partials(red, wave, g, r, acc0, acc1);
    __syncthreads();
    {   // T4 column -> red[tid] (own-slot overwrite, safe)
        const int c = tid >> 4, il = tid & 15;
        red[tid] = 2.0f * reduce8(red, tid) - Tf2[(size_t)c * NN + i0 + il];
    }
    __syncthreads();

    const int o = tid >> 4, il = tid & 15;
    float a0 = bias[o], a1 = bias[o + 32];
    for (int cc = 0; cc < CIN; ++cc) {
        const size_t off = (size_t)cc * NN + i0 + il;
        const float t0 = x[off], t1 = Tf1[off], t2 = Tf2[off], t3 = Tf3[off];
        const float t4 = red[cc * 16 + il];
        const float* th0 = theta + ((size_t)o * CIN + cc) * KF;
        const float* th1 = theta + ((size_t)(o + 32) * CIN + cc) * KF;
        a0 += t0 * th0[0] + t1 * th0[1] + t2 * th0[2] + t3 * th0[3] + t4 * th0[4];
        a1 += t0 * th1[0] + t1 * th1[1] + t2 * th1[2] + t3 * th1[3] + t4 * th1[4];
    }
    y[(size_t)o * NN + i0 + il]        = a0;
    y[(size_t)(o + 32) * NN + i0 + il] = a1;
}

extern "C" void kernel_launch(void* const* d_in, const int* in_sizes, int n_in,
                              void* d_out, int out_size, void* d_ws, size_t ws_size,
                              hipStream_t stream) {
    const float* L     = (const float*)d_in[0];
    const float* x     = (const float*)d_in[1];
    const float* theta = (const float*)d_in[2];
    const float* bias  = (const float*)d_in[3];
    float* y = (float*)d_out;

    const size_t TE = (size_t)CIN * NN;
    const size_t LE = (size_t)NN * NN;

    // ws: Lb tiled (128MB) | Tf1..Tf3 (1MB ea) | Tb0..Tb3 (0.5MB ea)
    char*  LbC = (char*)d_ws;
    float* Tf1 = (float*)(LbC + LE * 2);
    float* Tf2 = Tf1 + TE;
    float* Tf3 = Tf2 + TE;
    short* Tb0 = (short*)(Tf3 + TE);
    short* Tb1 = Tb0 + TE;
    short* Tb2 = Tb1 + TE;
    short* Tb3 = Tb2 + TE;

    cvt_kernel<<<256, 256, 0, stream>>>(x, Tb0);
    pass1_kernel<<<NN / 16, 512, 0, stream>>>(L, Tb0, LbC, Tf1, Tb1);
    passmid_kernel<<<NN / 16, 512, 0, stream>>>(LbC, Tb1, x,   Tf2, Tb2);  // T2
    passmid_kernel<<<NN / 16, 512, 0, stream>>>(LbC, Tb2, Tf1, Tf3, Tb3);  // T3
    pass4_kernel<<<NN / 16, 512, 0, stream>>>(LbC, Tb3, Tf2, x, Tf1, Tf3,
                                              theta, bias, y);             // T4 + einsum
}

// Round 10
// 248.597 us; speedup vs baseline: 1.1587x; 1.0143x over previous
//
#include <hip/hip_runtime.h>

#define NN 8192
#define CIN 32
#define COUT 64
#define KF 5

typedef __attribute__((ext_vector_type(8))) short bf16x8_t;
typedef __attribute__((ext_vector_type(4))) float f32x4_t;

typedef const __attribute__((address_space(1))) void* as1_t;
typedef __attribute__((address_space(3))) void* as3_t;
__device__ __forceinline__ void gll16(const void* g, void* l) {
    __builtin_amdgcn_global_load_lds((as1_t)g, (as3_t)l, 16, 0, 0);
}

// fp32 -> bf16 RNE
__device__ __forceinline__ short f2bf(float f) {
    unsigned u = __builtin_bit_cast(unsigned, f);
    unsigned r = (u + 0x7FFFu + ((u >> 16) & 1u)) >> 16;
    return (short)(unsigned short)r;
}

__device__ __forceinline__ bf16x8_t cvt8(float4 a, float4 b) {
    bf16x8_t v;
    v[0] = f2bf(a.x); v[1] = f2bf(a.y); v[2] = f2bf(a.z); v[3] = f2bf(a.w);
    v[4] = f2bf(b.x); v[5] = f2bf(b.y); v[6] = f2bf(b.z); v[7] = f2bf(b.w);
    return v;
}

// x fp32 -> bf16
__global__ void cvt_kernel(const float* __restrict__ src, short* __restrict__ dst) {
    int idx = blockIdx.x * 256 + threadIdx.x;
    float4 v = reinterpret_cast<const float4*>(src)[idx];
    short4 o;
    o.x = f2bf(v.x); o.y = f2bf(v.y); o.z = f2bf(v.z); o.w = f2bf(v.w);
    reinterpret_cast<short4*>(dst)[idx] = o;
}

// D layout (m89): col=lane&15 -> i, row=(lane>>4)*4+reg -> c
__device__ __forceinline__ void stash_partials(float* red, int wave, int g, int r,
                                               const f32x4_t& acc0, const f32x4_t& acc1) {
    const int base = wave * 512 + g * 64 + r;
#pragma unroll
    for (int t = 0; t < 4; ++t) {
        red[base + t * 16]       = acc0[t];
        red[base + t * 16 + 256] = acc1[t];
    }
}

__device__ __forceinline__ float reduce8(const float* red, int tid) {
    float s = red[tid];
#pragma unroll
    for (int w = 1; w < 8; ++w) s += red[w * 512 + tid];
    return s;
}

// ---- Pass 1 (R10): R1-proven direct fp32 L reads (128B runs per 4-lane cluster),
// inline cvt, Lb stored in tiled layout with fully-linear 1KB wave stores.
// Grid 512; 8 waves; i-tile 16; wave K-range 1024 = 32 steps. LDS = 16KB only.
__global__ __launch_bounds__(512, 4) void pass1_kernel(
    const float* __restrict__ L, const short* __restrict__ Tb0,
    char* __restrict__ LbC, float* __restrict__ Tf1, short* __restrict__ Tb1)
{
    __shared__ float red[4096];
    const int tid = threadIdx.x, wave = tid >> 6, lane = tid & 63;
    const int g = lane >> 4, r = lane & 15;
    const int t = blockIdx.x, i0 = t * 16;
    const int kw = wave * 1024;

    const float* Lrow = L   + (size_t)(i0 + r) * NN + kw + g * 8;
    const short* A0   = Tb0 + (size_t)r * NN        + kw + g * 8;
    const short* A1   = Tb0 + (size_t)(r + 16) * NN + kw + g * 8;
    // tiled Lb: tile t -> 256KB, wave -> 32KB; k-step it -> 1KB linear block
    char* LbW = LbC + (size_t)t * 262144 + wave * 32768 + lane * 16;

    f32x4_t acc0 = {0.f,0.f,0.f,0.f}, acc1 = {0.f,0.f,0.f,0.f};
    for (int it = 0; it < 32; ++it) {
        const int jl = it * 32;
        float4 l0 = *(const float4*)(Lrow + jl);
        float4 l1 = *(const float4*)(Lrow + jl + 4);
        bf16x8_t a0 = *(const bf16x8_t*)(A0 + jl);
        bf16x8_t a1 = *(const bf16x8_t*)(A1 + jl);
        bf16x8_t b = cvt8(l0, l1);
        *(bf16x8_t*)(LbW + it * 1024) = b;            // full-line linear store
        acc0 = __builtin_amdgcn_mfma_f32_16x16x32_bf16(a0, b, acc0, 0, 0, 0);
        acc1 = __builtin_amdgcn_mfma_f32_16x16x32_bf16(a1, b, acc1, 0, 0, 0);
    }

    stash_partials(red, wave, g, r, acc0, acc1);
    __syncthreads();
    const int c = tid >> 4, il = tid & 15;
    const float val = reduce8(red, tid);
    const size_t off = (size_t)c * NN + i0 + il;
    Tf1[off] = val;
    Tb1[off] = f2bf(val);
}

// Mid-pass core (R9-proven): wave-private K 1024 = 16 chunks of 64 cols, depth-2 DMA ring.
// Lb tiled: wave base 32KB; chunk c: 2KB linear = [m'0..7][row0..15][16B].
// A image per chunk: 4KB = [m'0..7][row0..31][16B].
__device__ __forceinline__ void mid_core(const char* __restrict__ LbW,
                                         const short* __restrict__ Abase,
                                         int wave, int lane, char* stg,
                                         f32x4_t& acc0, f32x4_t& acc1)
{
    const int g = lane >> 4, r = lane & 15;
    const int kw = wave * 1024;
    const char* srcL = LbW + lane * 16;
    const short* sA0 = Abase + (size_t)(lane & 31) * NN + kw + (lane >> 5) * 8;

#pragma unroll
    for (int c0 = 0; c0 < 2; ++c0) {     // prologue: chunks 0,1 (6 DMA each)
        char* Ld = stg + c0 * 6144;
        char* Ad = Ld + 2048;
        gll16(srcL + c0 * 2048,        Ld);
        gll16(srcL + c0 * 2048 + 1024, Ld + 1024);
#pragma unroll
        for (int j = 0; j < 4; ++j) gll16(sA0 + c0 * 64 + j * 16, Ad + j * 1024);
    }

    for (int c = 0; c < 16; ++c) {
        if (c < 15) asm volatile("s_waitcnt vmcnt(6)" ::: "memory");
        else        asm volatile("s_waitcnt vmcnt(0)" ::: "memory");
        const char* Ld = stg + (c & 1) * 6144;
        const char* Ad = Ld + 2048;
#pragma unroll
        for (int kk = 0; kk < 2; ++kk) {
            bf16x8_t b  = *(const bf16x8_t*)(Ld + (kk * 4 + g) * 256 + r * 16);
            bf16x8_t a0 = *(const bf16x8_t*)(Ad + (kk * 4 + g) * 512 + r * 16);
            bf16x8_t a1 = *(const bf16x8_t*)(Ad + (kk * 4 + g) * 512 + 256 + r * 16);
            acc0 = __builtin_amdgcn_mfma_f32_16x16x32_bf16(a0, b, acc0, 0, 0, 0);
            acc1 = __builtin_amdgcn_mfma_f32_16x16x32_bf16(a1, b, acc1, 0, 0, 0);
        }
        if (c < 14) {
            asm volatile("s_waitcnt lgkmcnt(0)" ::: "memory");
            const int cn = c + 2;
            char* Ldn = stg + (cn & 1) * 6144;
            char* Adn = Ldn + 2048;
            gll16(srcL + cn * 2048,        Ldn);
            gll16(srcL + cn * 2048 + 1024, Ldn + 1024);
#pragma unroll
            for (int j = 0; j < 4; ++j) gll16(sA0 + cn * 64 + j * 16, Adn + j * 1024);
        }
    }
}

// ---- Mid passes (2,3): T_next = 2*(Tcur @ L^T) - Tprev
__global__ __launch_bounds__(512, 2) void passmid_kernel(
    const char* __restrict__ LbC, const short* __restrict__ A,
    const float* __restrict__ Tprev, float* __restrict__ Tf, short* __restrict__ Tb)
{
    __shared__ float red[4096];
    __shared__ __align__(16) char stg[8][12288];
    const int tid = threadIdx.x, wave = tid >> 6, lane = tid & 63;
    const int g = lane >> 4, r = lane & 15;
    const int t = blockIdx.x, i0 = t * 16;

    f32x4_t acc0 = {0.f,0.f,0.f,0.f}, acc1 = {0.f,0.f,0.f,0.f};
    mid_core(LbC + (size_t)t * 262144 + wave * 32768, A, wave, lane, stg[wave], acc0, acc1);

    stash_partials(red, wave, g, r, acc0, acc1);
    __syncthreads();
    const int c = tid >> 4, il = tid & 15;
    const size_t off = (size_t)c * NN + i0 + il;
    const float val = 2.0f * reduce8(red, tid) - Tprev[off];
    Tf[off] = val;
    Tb[off] = f2bf(val);
}

// ---- Pass 4 + fused final einsum (T4 stays in LDS)
__global__ __launch_bounds__(512, 2) void pass4_kernel(
    const char* __restrict__ LbC, const short* __restrict__ A,
    const float* __restrict__ Tf2, const float* __restrict__ x,
    const float* __restrict__ Tf1, const float* __restrict__ Tf3,
    const float* __restrict__ theta, const float* __restrict__ bias,
    float* __restrict__ y)
{
    __shared__ float red[4096];
    __shared__ __align__(16) char stg[8][12288];
    const int tid = threadIdx.x, wave = tid >> 6, lane = tid & 63;
    const int g = lane >> 4, r = lane & 15;
    const int t = blockIdx.x, i0 = t * 16;

    f32x4_t acc0 = {0.f,0.f,0.f,0.f}, acc1 = {0.f,0.f,0.f,0.f};
    mid_core(LbC + (size_t)t * 262144 + wave * 32768, A, wave, lane, stg[wave], acc0, acc1);

    stash_partials(red, wave, g, r, acc0, acc1);
    __syncthreads();
    {   // T4 column -> red[tid] (own-slot overwrite, safe)
        const int c = tid >> 4, il = tid & 15;
        red[tid] = 2.0f * reduce8(red, tid) - Tf2[(size_t)c * NN + i0 + il];
    }
    __syncthreads();

    const int o = tid >> 4, il = tid & 15;
    float a0 = bias[o], a1 = bias[o + 32];
    for (int cc = 0; cc < CIN; ++cc) {
        const size_t off = (size_t)cc * NN + i0 + il;
        const float t0 = x[off], t1 = Tf1[off], t2 = Tf2[off], t3 = Tf3[off];
        const float t4 = red[cc * 16 + il];
        const float* th0 = theta + ((size_t)o * CIN + cc) * KF;
        const float* th1 = theta + ((size_t)(o + 32) * CIN + cc) * KF;
        a0 += t0 * th0[0] + t1 * th0[1] + t2 * th0[2] + t3 * th0[3] + t4 * th0[4];
        a1 += t0 * th1[0] + t1 * th1[1] + t2 * th1[2] + t3 * th1[3] + t4 * th1[4];
    }
    y[(size_t)o * NN + i0 + il]        = a0;
    y[(size_t)(o + 32) * NN + i0 + il] = a1;
}

extern "C" void kernel_launch(void* const* d_in, const int* in_sizes, int n_in,
                              void* d_out, int out_size, void* d_ws, size_t ws_size,
                              hipStream_t stream) {
    const float* L     = (const float*)d_in[0];
    const float* x     = (const float*)d_in[1];
    const float* theta = (const float*)d_in[2];
    const float* bias  = (const float*)d_in[3];
    float* y = (float*)d_out;

    const size_t TE = (size_t)CIN * NN;
    const size_t LE = (size_t)NN * NN;

    // ws: Lb tiled (128MB) | Tf1..Tf3 (1MB ea) | Tb0..Tb3 (0.5MB ea)
    char*  LbC = (char*)d_ws;
    float* Tf1 = (float*)(LbC + LE * 2);
    float* Tf2 = Tf1 + TE;
    float* Tf3 = Tf2 + TE;
    short* Tb0 = (short*)(Tf3 + TE);
    short* Tb1 = Tb0 + TE;
    short* Tb2 = Tb1 + TE;
    short* Tb3 = Tb2 + TE;

    cvt_kernel<<<256, 256, 0, stream>>>(x, Tb0);
    pass1_kernel<<<NN / 16, 512, 0, stream>>>(L, Tb0, LbC, Tf1, Tb1);
    passmid_kernel<<<NN / 16, 512, 0, stream>>>(LbC, Tb1, x,   Tf2, Tb2);  // T2
    passmid_kernel<<<NN / 16, 512, 0, stream>>>(LbC, Tb2, Tf1, Tf3, Tb3);  // T3
    pass4_kernel<<<NN / 16, 512, 0, stream>>>(LbC, Tb3, Tf2, x, Tf1, Tf3,
                                              theta, bias, y);             // T4 + einsum
}

// Round 12
// 242.657 us; speedup vs baseline: 1.1871x; 1.0245x over previous
//
#include <hip/hip_runtime.h>

#define NN 8192
#define CIN 32
#define COUT 64
#define KF 5

typedef __attribute__((ext_vector_type(8))) short bf16x8_t;
typedef __attribute__((ext_vector_type(4))) float f32x4_t;

typedef const __attribute__((address_space(1))) void* as1_t;
typedef __attribute__((address_space(3))) void* as3_t;
__device__ __forceinline__ void gll16(const void* g, void* l) {
    __builtin_amdgcn_global_load_lds((as1_t)g, (as3_t)l, 16, 0, 0);
}

// fp32 -> bf16 RNE
__device__ __forceinline__ short f2bf(float f) {
    unsigned u = __builtin_bit_cast(unsigned, f);
    unsigned r = (u + 0x7FFFu + ((u >> 16) & 1u)) >> 16;
    return (short)(unsigned short)r;
}

__device__ __forceinline__ bf16x8_t cvt8v(f32x4_t a, f32x4_t b) {
    bf16x8_t v;
    v[0] = f2bf(a[0]); v[1] = f2bf(a[1]); v[2] = f2bf(a[2]); v[3] = f2bf(a[3]);
    v[4] = f2bf(b[0]); v[5] = f2bf(b[1]); v[6] = f2bf(b[2]); v[7] = f2bf(b[3]);
    return v;
}

// x fp32 -> bf16
__global__ void cvt_kernel(const float* __restrict__ src, short* __restrict__ dst) {
    int idx = blockIdx.x * 256 + threadIdx.x;
    float4 v = reinterpret_cast<const float4*>(src)[idx];
    short4 o;
    o.x = f2bf(v.x); o.y = f2bf(v.y); o.z = f2bf(v.z); o.w = f2bf(v.w);
    reinterpret_cast<short4*>(dst)[idx] = o;
}

// D layout (m89): col=lane&15 -> i, row=(lane>>4)*4+reg -> c
__device__ __forceinline__ void stash_partials(float* red, int wave, int g, int r,
                                               const f32x4_t& acc0, const f32x4_t& acc1) {
    const int base = wave * 512 + g * 64 + r;
#pragma unroll
    for (int t = 0; t < 4; ++t) {
        red[base + t * 16]       = acc0[t];
        red[base + t * 16 + 256] = acc1[t];
    }
}

__device__ __forceinline__ float reduce8(const float* red, int tid) {
    float s = red[tid];
#pragma unroll
    for (int w = 1; w < 8; ++w) s += red[w * 512 + tid];
    return s;
}

// ---- Pass 1 (R11): K split 2-way -> grid 1024 -> 4 blocks/CU (32 waves/CU).
// Non-temporal fp32 L reads (read-once; keep L3 for Lb); Lb stored normally in
// tiled layout (linear 1KB wave stores). Wave K-chain = 512 (16 iters).
__global__ __launch_bounds__(512, 8) void pass1_kernel(
    const float* __restrict__ L, const short* __restrict__ Tb0,
    char* __restrict__ LbC, float* __restrict__ part)
{
    __shared__ float red[4096];
    const int tid = threadIdx.x, wave = tid >> 6, lane = tid & 63;
    const int g = lane >> 4, r = lane & 15;
    const int t = blockIdx.x >> 1, h = blockIdx.x & 1;
    const int i0 = t * 16;
    const int kw = h * 4096 + wave * 512;

    const float* Lrow = L   + (size_t)(i0 + r) * NN + kw + g * 8;
    const short* A0   = Tb0 + (size_t)r * NN        + kw + g * 8;
    const short* A1   = Tb0 + (size_t)(r + 16) * NN + kw + g * 8;
    // tiled Lb byte offset for col-block m (32 cols) of mid-wave w' = kw/1024:
    //   t*262144 + w'*32768 + m*1024 + g*256 + r*16   (lane*16 == g*256+r*16)
    char* LbW = LbC + (size_t)t * 262144 + (size_t)(h * 4 + (wave >> 1)) * 32768
              + (wave & 1) * 16384 + lane * 16;

    f32x4_t acc0 = {0.f,0.f,0.f,0.f}, acc1 = {0.f,0.f,0.f,0.f};
    for (int it = 0; it < 16; ++it) {
        const int jl = it * 32;
        f32x4_t l0 = __builtin_nontemporal_load(reinterpret_cast<const f32x4_t*>(Lrow + jl));
        f32x4_t l1 = __builtin_nontemporal_load(reinterpret_cast<const f32x4_t*>(Lrow + jl) + 1);
        bf16x8_t a0 = *(const bf16x8_t*)(A0 + jl);
        bf16x8_t a1 = *(const bf16x8_t*)(A1 + jl);
        bf16x8_t b = cvt8v(l0, l1);
        *(bf16x8_t*)(LbW + it * 1024) = b;            // linear 1KB store (cached)
        acc0 = __builtin_amdgcn_mfma_f32_16x16x32_bf16(a0, b, acc0, 0, 0, 0);
        acc1 = __builtin_amdgcn_mfma_f32_16x16x32_bf16(a1, b, acc1, 0, 0, 0);
    }

    stash_partials(red, wave, g, r, acc0, acc1);
    __syncthreads();
    const int c = tid >> 4, il = tid & 15;
    part[(size_t)h * CIN * NN + (size_t)c * NN + i0 + il] = reduce8(red, tid);
}

// ---- T1 = part0 + part1 (fixed order, deterministic); write fp32 + bf16
__global__ __launch_bounds__(256) void combine1_kernel(
    const float* __restrict__ part, float* __restrict__ Tf1, short* __restrict__ Tb1)
{
    const int idx = blockIdx.x * 256 + threadIdx.x;   // quad index, CIN*NN/4
    const float4 p0 = reinterpret_cast<const float4*>(part)[idx];
    const float4 p1 = reinterpret_cast<const float4*>(part + (size_t)CIN * NN)[idx];
    float4 v;
    v.x = p0.x + p1.x; v.y = p0.y + p1.y; v.z = p0.z + p1.z; v.w = p0.w + p1.w;
    reinterpret_cast<float4*>(Tf1)[idx] = v;
    short4 b;
    b.x = f2bf(v.x); b.y = f2bf(v.y); b.z = f2bf(v.z); b.w = f2bf(v.w);
    reinterpret_cast<short4*>(Tb1)[idx] = b;
}

// Mid-pass core (R9-proven): wave-private K 1024 = 16 chunks of 64 cols, depth-2 DMA ring.
// Lb tiled: wave base 32KB; chunk c: 2KB linear = [m'0..7][row0..15][16B].
// A image per chunk: 4KB = [m'0..7][row0..31][16B].
__device__ __forceinline__ void mid_core(const char* __restrict__ LbW,
                                         const short* __restrict__ Abase,
                                         int wave, int lane, char* stg,
                                         f32x4_t& acc0, f32x4_t& acc1)
{
    const int g = lane >> 4, r = lane & 15;
    const int kw = wave * 1024;
    const char* srcL = LbW + lane * 16;
    const short* sA0 = Abase + (size_t)(lane & 31) * NN + kw + (lane >> 5) * 8;

#pragma unroll
    for (int c0 = 0; c0 < 2; ++c0) {     // prologue: chunks 0,1 (6 DMA each)
        char* Ld = stg + c0 * 6144;
        char* Ad = Ld + 2048;
        gll16(srcL + c0 * 2048,        Ld);
        gll16(srcL + c0 * 2048 + 1024, Ld + 1024);
#pragma unroll
        for (int j = 0; j < 4; ++j) gll16(sA0 + c0 * 64 + j * 16, Ad + j * 1024);
    }

    for (int c = 0; c < 16; ++c) {
        if (c < 15) asm volatile("s_waitcnt vmcnt(6)" ::: "memory");
        else        asm volatile("s_waitcnt vmcnt(0)" ::: "memory");
        const char* Ld = stg + (c & 1) * 6144;
        const char* Ad = Ld + 2048;
#pragma unroll
        for (int kk = 0; kk < 2; ++kk) {
            bf16x8_t b  = *(const bf16x8_t*)(Ld + (kk * 4 + g) * 256 + r * 16);
            bf16x8_t a0 = *(const bf16x8_t*)(Ad + (kk * 4 + g) * 512 + r * 16);
            bf16x8_t a1 = *(const bf16x8_t*)(Ad + (kk * 4 + g) * 512 + 256 + r * 16);
            acc0 = __builtin_amdgcn_mfma_f32_16x16x32_bf16(a0, b, acc0, 0, 0, 0);
            acc1 = __builtin_amdgcn_mfma_f32_16x16x32_bf16(a1, b, acc1, 0, 0, 0);
        }
        if (c < 14) {
            asm volatile("s_waitcnt lgkmcnt(0)" ::: "memory");
            const int cn = c + 2;
            char* Ldn = stg + (cn & 1) * 6144;
            char* Adn = Ldn + 2048;
            gll16(srcL + cn * 2048,        Ldn);
            gll16(srcL + cn * 2048 + 1024, Ldn + 1024);
#pragma unroll
            for (int j = 0; j < 4; ++j) gll16(sA0 + cn * 64 + j * 16, Adn + j * 1024);
        }
    }
}

// ---- Mid passes (2,3): T_next = 2*(Tcur @ L^T) - Tprev
__global__ __launch_bounds__(512, 2) void passmid_kernel(
    const char* __restrict__ LbC, const short* __restrict__ A,
    const float* __restrict__ Tprev, float* __restrict__ Tf, short* __restrict__ Tb)
{
    __shared__ float red[4096];
    __shared__ __align__(16) char stg[8][12288];
    const int tid = threadIdx.x, wave = tid >> 6, lane = tid & 63;
    const int g = lane >> 4, r = lane & 15;
    const int t = blockIdx.x, i0 = t * 16;

    f32x4_t acc0 = {0.f,0.f,0.f,0.f}, acc1 = {0.f,0.f,0.f,0.f};
    mid_core(LbC + (size_t)t * 262144 + wave * 32768, A, wave, lane, stg[wave], acc0, acc1);

    stash_partials(red, wave, g, r, acc0, acc1);
    __syncthreads();
    const int c = tid >> 4, il = tid & 15;
    const size_t off = (size_t)c * NN + i0 + il;
    const float val = 2.0f * reduce8(red, tid) - Tprev[off];
    Tf[off] = val;
    Tb[off] = f2bf(val);
}

// ---- Pass 4 + fused final einsum (T4 stays in LDS)
__global__ __launch_bounds__(512, 2) void pass4_kernel(
    const char* __restrict__ LbC, const short* __restrict__ A,
    const float* __restrict__ Tf2, const float* __restrict__ x,
    const float* __restrict__ Tf1, const float* __restrict__ Tf3,
    const float* __restrict__ theta, const float* __restrict__ bias,
    float* __restrict__ y)
{
    __shared__ float red[4096];
    __shared__ __align__(16) char stg[8][12288];
    const int tid = threadIdx.x, wave = tid >> 6, lane = tid & 63;
    const int g = lane >> 4, r = lane & 15;
    const int t = blockIdx.x, i0 = t * 16;

    f32x4_t acc0 = {0.f,0.f,0.f,0.f}, acc1 = {0.f,0.f,0.f,0.f};
    mid_core(LbC + (size_t)t * 262144 + wave * 32768, A, wave, lane, stg[wave], acc0, acc1);

    stash_partials(red, wave, g, r, acc0, acc1);
    __syncthreads();
    {   // T4 column -> red[tid] (own-slot overwrite, safe)
        const int c = tid >> 4, il = tid & 15;
        red[tid] = 2.0f * reduce8(red, tid) - Tf2[(size_t)c * NN + i0 + il];
    }
    __syncthreads();

    const int o = tid >> 4, il = tid & 15;
    float a0 = bias[o], a1 = bias[o + 32];
    for (int cc = 0; cc < CIN; ++cc) {
        const size_t off = (size_t)cc * NN + i0 + il;
        const float t0 = x[off], t1 = Tf1[off], t2 = Tf2[off], t3 = Tf3[off];
        const float t4 = red[cc * 16 + il];
        const float* th0 = theta + ((size_t)o * CIN + cc) * KF;
        const float* th1 = theta + ((size_t)(o + 32) * CIN + cc) * KF;
        a0 += t0 * th0[0] + t1 * th0[1] + t2 * th0[2] + t3 * th0[3] + t4 * th0[4];
        a1 += t0 * th1[0] + t1 * th1[1] + t2 * th1[2] + t3 * th1[3] + t4 * th1[4];
    }
    y[(size_t)o * NN + i0 + il]        = a0;
    y[(size_t)(o + 32) * NN + i0 + il] = a1;
}

extern "C" void kernel_launch(void* const* d_in, const int* in_sizes, int n_in,
                              void* d_out, int out_size, void* d_ws, size_t ws_size,
                              hipStream_t stream) {
    const float* L     = (const float*)d_in[0];
    const float* x     = (const float*)d_in[1];
    const float* theta = (const float*)d_in[2];
    const float* bias  = (const float*)d_in[3];
    float* y = (float*)d_out;

    const size_t TE = (size_t)CIN * NN;
    const size_t LE = (size_t)NN * NN;

    // ws: Lb tiled (128MB) | Tf1..Tf3 (1MB ea) | Tb0..Tb3 (0.5MB ea) | part (2MB)
    char*  LbC = (char*)d_ws;
    float* Tf1 = (float*)(LbC + LE * 2);
    float* Tf2 = Tf1 + TE;
    float* Tf3 = Tf2 + TE;
    short* Tb0 = (short*)(Tf3 + TE);
    short* Tb1 = Tb0 + TE;
    short* Tb2 = Tb1 + TE;
    short* Tb3 = Tb2 + TE;
    float* part = (float*)(Tb3 + TE);

    cvt_kernel<<<256, 256, 0, stream>>>(x, Tb0);
    pass1_kernel<<<NN / 8, 512, 0, stream>>>(L, Tb0, LbC, part);
    combine1_kernel<<<256, 256, 0, stream>>>(part, Tf1, Tb1);
    passmid_kernel<<<NN / 16, 512, 0, stream>>>(LbC, Tb1, x,   Tf2, Tb2);  // T2
    passmid_kernel<<<NN / 16, 512, 0, stream>>>(LbC, Tb2, Tf1, Tf3, Tb3);  // T3
    pass4_kernel<<<NN / 16, 512, 0, stream>>>(LbC, Tb3, Tf2, x, Tf1, Tf3,
                                              theta, bias, y);             // T4 + einsum
}